// Round 7
// baseline (42255.988 us; speedup 1.0000x reference)
//
#include <hip/hip_runtime.h>
#include <math.h>

#define BSZ 1024
#define NNODE 200
#define DH 512
#define DK 512
#define NSTEP 200

// ---------------- threefry2x32 (JAX-exact, partitionable mode) ----------------
__device__ __forceinline__ unsigned rotl32(unsigned x, int r) {
  return (x << r) | (x >> (32 - r));
}

__device__ __forceinline__ void tf2x32(unsigned k0, unsigned k1,
                                       unsigned c0, unsigned c1,
                                       unsigned& o0, unsigned& o1) {
  unsigned ks2 = k0 ^ k1 ^ 0x1BD11BDAu;
  unsigned x0 = c0 + k0, x1 = c1 + k1;
#define TF_RND(r) { x0 += x1; x1 = rotl32(x1, (r)); x1 ^= x0; }
  TF_RND(13) TF_RND(15) TF_RND(26) TF_RND(6)
  x0 += k1;  x1 += ks2 + 1u;
  TF_RND(17) TF_RND(29) TF_RND(16) TF_RND(24)
  x0 += ks2; x1 += k0 + 2u;
  TF_RND(13) TF_RND(15) TF_RND(26) TF_RND(6)
  x0 += k0;  x1 += k1 + 3u;
  TF_RND(17) TF_RND(29) TF_RND(16) TF_RND(24)
  x0 += k1;  x1 += ks2 + 4u;
  TF_RND(13) TF_RND(15) TF_RND(26) TF_RND(6)
  x0 += ks2; x1 += k0 + 5u;
#undef TF_RND
  o0 = x0; o1 = x1;
}

// split foldlike: keys[i] = threefry2x32(base_key, (0, i)); key = (o0, o1)
__device__ __forceinline__ void step_key(int i, unsigned& k0, unsigned& k1) {
  tf2x32(0u, 42u, 0u, (unsigned)i, k0, k1);
}
// random_bits partitionable 32-bit: bits[m] = o0 ^ o1 with counter (0, m)
__device__ __forceinline__ unsigned elem_bits(unsigned k0, unsigned k1, unsigned m) {
  unsigned o0, o1;
  tf2x32(k0, k1, 0u, m, o0, o1);
  return o0 ^ o1;
}

// -------- XLA f32 tanh (EmitFastTanh, with_fma=true -> fmuladd Horner) -------
__device__ __forceinline__ float xla_tanh_f32(float x) {
  const float kMax = 7.90531110763549805f;
  float xc = fminf(fmaxf(x, -kMax), kMax);
  float x2 = xc * xc;
  float p = -2.76076847742355e-16f;
  p = __builtin_fmaf(x2, p, 2.00018790482477e-13f);
  p = __builtin_fmaf(x2, p, -8.60467152213735e-11f);
  p = __builtin_fmaf(x2, p, 5.12229709037114e-08f);
  p = __builtin_fmaf(x2, p, 1.48572235717979e-05f);
  p = __builtin_fmaf(x2, p, 6.37261928875436e-04f);
  p = __builtin_fmaf(x2, p, 4.89352455891786e-03f);
  float num = xc * p;
  float q = 1.19825839466702e-06f;
  q = __builtin_fmaf(x2, q, 1.18534705686654e-04f);
  q = __builtin_fmaf(x2, q, 2.26843463243900e-03f);
  q = __builtin_fmaf(x2, q, 4.89352518554385e-03f);
  float r = num / q;
  return (fabsf(x) < 0.0004f) ? x : r;
}

// ---------------- XLA f32 log (Cephes, plain fmul/fadd as in VF32Log) --------
__device__ __forceinline__ float xla_log_f32(float x) {
#pragma clang fp contract(off)
  unsigned bits = __float_as_uint(x);
  int e = (int)((bits >> 23) & 0xffu) - 126;          // x = m * 2^e, m in [0.5,1)
  float m = __uint_as_float((bits & 0x007fffffu) | 0x3f000000u);
  bool c = m < 0.707106781186547524f;                 // sqrt(0.5)
  e = c ? (e - 1) : e;
  m = c ? (m + m) : m;
  m = m - 1.0f;
  float z = m * m;
  float y = 7.0376836292e-2f;
  y = y * m + (-1.1514610310e-1f);
  y = y * m + 1.1676998740e-1f;
  y = y * m + (-1.2420140846e-1f);
  y = y * m + 1.4249322787e-1f;
  y = y * m + (-1.6668057665e-1f);
  y = y * m + 2.0000714765e-1f;
  y = y * m + (-2.4999993993e-1f);
  y = y * m + 3.3333331174e-1f;
  y = y * m;
  y = y * z;
  float ef = (float)e;
  float t1 = ef * (-2.12194440e-4f);
  y = y + t1;
  float t2 = z * 0.5f;
  y = y - t2;
  float r = m + y;
  float t3 = ef * 0.693359375f;
  r = r + t3;
  return r;
}

// ---------------- setup kernels (f32, gold-faithful orders) ----------------

// Hbar[b][d] = (sum over n ascending, plain f32 adds) / 200.0f
// (XLA column reduction: sequential over reduced dim, vectorized over minor)
__global__ void k_hbar(const float* __restrict__ H, float* __restrict__ Hbar) {
#pragma clang fp contract(off)
  int idx = blockIdx.x * 256 + threadIdx.x;  // 1024*512
  int b = idx >> 9, d = idx & 511;
  const float* p = H + (size_t)b * NNODE * DH + d;
  float s = 0.0f;
  for (int n = 0; n < NNODE; n++) s = s + p[(size_t)n * DH];
  Hbar[idx] = s / 200.0f;
}

// K[b][n][k] = FMA-chain over d ascending (Eigen gemm model)
__global__ __launch_bounds__(256) void k_K(const float* __restrict__ H,
                                           const float* __restrict__ WK,
                                           float* __restrict__ K) {
  __shared__ float hr[8][DH];  // 16 KiB
  int g = blockIdx.x;          // 1024*25 blocks, 8 rows each
  int b = g / 25;
  int r0 = (g % 25) * 8;
  int t = threadIdx.x;
  const float* Hb = H + (size_t)b * NNODE * DH + (size_t)r0 * DH;
  for (int e = t; e < 8 * DH; e += 256) hr[e >> 9][e & 511] = Hb[e];
  __syncthreads();
  int k0 = t, k1 = t + 256;
  float a[8][2];
#pragma unroll
  for (int r = 0; r < 8; r++) { a[r][0] = 0.0f; a[r][1] = 0.0f; }
  for (int d = 0; d < DH; d++) {
    float w0 = WK[(size_t)d * DK + k0], w1 = WK[(size_t)d * DK + k1];
#pragma unroll
    for (int r = 0; r < 8; r++) {
      a[r][0] = __builtin_fmaf(hr[r][d], w0, a[r][0]);
      a[r][1] = __builtin_fmaf(hr[r][d], w1, a[r][1]);
    }
  }
  float* Kb = K + (size_t)b * NNODE * DK + (size_t)r0 * DK;
#pragma unroll
  for (int r = 0; r < 8; r++) {
    Kb[(size_t)r * DK + k0] = a[r][0];
    Kb[(size_t)r * DK + k1] = a[r][1];
  }
}

// acc[b][j] = FMA-chain k=0..511 of Hbar[b,k]*WQ[k,j] (prefix of the 1536-chain)
__global__ __launch_bounds__(256) void k_acc512(const float* __restrict__ Hbar,
                                                const float* __restrict__ WQ,
                                                float* __restrict__ acc) {
  __shared__ float hb[DH];
  int b = blockIdx.x, t = threadIdx.x;
  for (int e = t; e < DH; e += 256) hb[e] = Hbar[(size_t)b * DH + e];
  __syncthreads();
  int j0 = t, j1 = t + 256;
  float a0 = 0.0f, a1 = 0.0f;
  for (int k = 0; k < DH; k++) {
    float w0 = WQ[(size_t)k * DK + j0], w1 = WQ[(size_t)k * DK + j1];
    a0 = __builtin_fmaf(hb[k], w0, a0);
    a1 = __builtin_fmaf(hb[k], w1, a1);
  }
  acc[(size_t)b * DK + j0] = a0;
  acc[(size_t)b * DK + j1] = a1;
}

// Q0 = continue chain with v1 part (k=512..1023) then vf part (k=1024..1535)
__global__ __launch_bounds__(256) void k_q0(const float* __restrict__ acc,
                                            const float* __restrict__ WQ,
                                            const float* __restrict__ v1,
                                            const float* __restrict__ vf,
                                            float* __restrict__ Q) {
  __shared__ float s1[DH], s2[DH];
  int b = blockIdx.x, t = threadIdx.x;
  for (int e = t; e < DH; e += 256) { s1[e] = v1[e]; s2[e] = vf[e]; }
  __syncthreads();
  int j0 = t, j1 = t + 256;
  float a0 = acc[(size_t)b * DK + j0], a1 = acc[(size_t)b * DK + j1];
  for (int k = 0; k < DH; k++) {
    float w0 = WQ[(size_t)(512 + k) * DK + j0], w1 = WQ[(size_t)(512 + k) * DK + j1];
    a0 = __builtin_fmaf(s1[k], w0, a0);
    a1 = __builtin_fmaf(s1[k], w1, a1);
  }
  for (int k = 0; k < DH; k++) {
    float w0 = WQ[(size_t)(1024 + k) * DK + j0], w1 = WQ[(size_t)(1024 + k) * DK + j1];
    a0 = __builtin_fmaf(s2[k], w0, a0);
    a1 = __builtin_fmaf(s2[k], w1, a1);
  }
  Q[(size_t)b * DK + j0] = a0;
  Q[(size_t)b * DK + j1] = a1;
}

// Q (steps>=1) = acc chain continued with Hpi part then Hpi0 (frozen) part.
__global__ __launch_bounds__(256) void k_q(const float* __restrict__ acc,
                                           const float* __restrict__ WQ,
                                           const float* __restrict__ Hpi,
                                           const float* __restrict__ Hpi0,
                                           float* __restrict__ Q) {
  __shared__ float hp[4][DH], hp0[4][DH];  // 16 KiB
  int b0 = blockIdx.x * 4, t = threadIdx.x;
  for (int e = t; e < 4 * DH; e += 256) {
    hp[e >> 9][e & 511]  = Hpi[(size_t)b0 * DH + e];
    hp0[e >> 9][e & 511] = Hpi0[(size_t)b0 * DH + e];
  }
  __syncthreads();
  int j0 = t, j1 = t + 256;
  float a[4][2];
#pragma unroll
  for (int r = 0; r < 4; r++) {
    a[r][0] = acc[(size_t)(b0 + r) * DK + j0];
    a[r][1] = acc[(size_t)(b0 + r) * DK + j1];
  }
  for (int k = 0; k < DH; k++) {
    float w0 = WQ[(size_t)(512 + k) * DK + j0], w1 = WQ[(size_t)(512 + k) * DK + j1];
#pragma unroll
    for (int r = 0; r < 4; r++) {
      a[r][0] = __builtin_fmaf(hp[r][k], w0, a[r][0]);
      a[r][1] = __builtin_fmaf(hp[r][k], w1, a[r][1]);
    }
  }
  for (int k = 0; k < DH; k++) {
    float w0 = WQ[(size_t)(1024 + k) * DK + j0], w1 = WQ[(size_t)(1024 + k) * DK + j1];
#pragma unroll
    for (int r = 0; r < 4; r++) {
      a[r][0] = __builtin_fmaf(hp0[r][k], w0, a[r][0]);
      a[r][1] = __builtin_fmaf(hp0[r][k], w1, a[r][1]);
    }
  }
#pragma unroll
  for (int r = 0; r < 4; r++) {
    Q[(size_t)(b0 + r) * DK + j0] = a[r][0];
    Q[(size_t)(b0 + r) * DK + j1] = a[r][1];
  }
}

__global__ void k_copy(const float* __restrict__ src, float* __restrict__ dst) {
  int i = blockIdx.x * 256 + threadIdx.x;
  dst[i] = src[i];
}

// ---------------- per-step: U, logits, gumbel, argmax, gather ----------------
// U: XLA EmitVectorizedReduce model, W=16 (AVX-512 host): 16 strided lane
// accumulators (k mod 16), separate mul/add, then 4-stage shuffle-halving tree.
__global__ __launch_bounds__(256) void k_step(const float* __restrict__ K,
                                              const float* __restrict__ Q,
                                              const float* __restrict__ H,
                                              float* __restrict__ Hpi,
                                              int* __restrict__ out, int step) {
  __shared__ float Kl[NNODE][65];  // 52 KB, padded
  __shared__ float Ql[DK];
  __shared__ float zl[NNODE];
  __shared__ int   pil;
  int b = blockIdx.x, t = threadIdx.x;
  for (int e = t; e < DK; e += 256) Ql[e] = Q[(size_t)b * DK + e];
  const float* Kb = K + (size_t)b * NNODE * DK;
  float l[16];
#pragma unroll
  for (int j = 0; j < 16; j++) l[j] = 0.0f;
  for (int c = 0; c < 8; c++) {  // k-chunks ASCENDING (16 | 64 => lane map holds)
    __syncthreads();
    for (int it = 0; it < 50; it++) {
      int idx = it * 256 + t;
      int row = idx >> 6, col = idx & 63;
      Kl[row][col] = Kb[(size_t)row * DK + c * 64 + col];
    }
    __syncthreads();
    if (t < NNODE) {
#pragma clang fp contract(off)
      const float* qp = Ql + c * 64;
#pragma unroll
      for (int kk = 0; kk < 64; kk += 16) {
#pragma unroll
        for (int j = 0; j < 16; j++) {
          float prod = Kl[t][kk + j] * qp[kk + j];  // separate mul rounding
          l[j] = l[j] + prod;                       // vector fadd accumulate
        }
      }
    }
  }
  if (t < NNODE) {
#pragma clang fp contract(off)
    // shuffle-halving horizontal reduce over 16 lanes:
#pragma unroll
    for (int j = 0; j < 8; j++) l[j] = l[j] + l[j + 8];
#pragma unroll
    for (int j = 0; j < 4; j++) l[j] = l[j] + l[j + 4];
#pragma unroll
    for (int j = 0; j < 2; j++) l[j] = l[j] + l[j + 2];
    float U = l[0] + l[1];
    const float inv = 1.0f / sqrtf(512.0f);   // const-folded, correctly rounded
    float u = U * inv;
    float logit = 10.0f * xla_tanh_f32(u);
    unsigned k0, k1;
    step_key(step, k0, k1);
    unsigned bits = elem_bits(k0, k1, (unsigned)(b * NNODE + t));
    unsigned fb = (bits >> 9) | 0x3F800000u;
    float uf = __uint_as_float(fb) - 1.0f;    // [0,1), exact
    const float tinyf = 1.17549435e-38f;
    float v = uf * 1.0f;                      // * (maxval-minval) == 1.0f, exact
    v = v + tinyf;                            // + minval
    v = fmaxf(tinyf, v);
    float L1 = xla_log_f32(v);
    float g = -xla_log_f32(-L1);
    zl[t] = g + logit;                        // gumbel + logits (categorical order)
  }
  __syncthreads();
  if (t < 64) {  // wave 0: argmax, first-occurrence tie rule, f32 compares
    float bv = -__builtin_inff();
    int bi = 0;
    for (int n = t; n < NNODE; n += 64) {
      float zv = zl[n];
      if (zv > bv) { bv = zv; bi = n; }
    }
    for (int off = 32; off; off >>= 1) {
      float ov = __shfl_down(bv, off);
      int   oi = __shfl_down(bi, off);
      if (ov > bv || (ov == bv && oi < bi)) { bv = ov; bi = oi; }
    }
    if (t == 0) pil = bi;
  }
  __syncthreads();
  int pi = pil;
  if (t == 0) {
    out[b * (NSTEP + 1) + step + 1] = pi;
    if (step == 0) out[b * (NSTEP + 1)] = pi;  // Pi duplicates step-0 pick at col 0
  }
  const float* src = H + (size_t)b * NNODE * DH + (size_t)pi * DH;
  for (int e = t; e < DH; e += 256) Hpi[(size_t)b * DH + e] = src[e];  // exact copy
}

extern "C" void kernel_launch(void* const* d_in, const int* in_sizes, int n_in,
                              void* d_out, int out_size, void* d_ws, size_t ws_size,
                              hipStream_t stream) {
  (void)in_sizes; (void)n_in; (void)out_size; (void)ws_size;
  const float* H  = (const float*)d_in[1];
  const float* WQ = (const float*)d_in[2];
  const float* WK = (const float*)d_in[3];
  const float* v1 = (const float*)d_in[4];
  const float* vf = (const float*)d_in[5];
  int* out = (int*)d_out;

  float* ws = (float*)d_ws;
  const size_t KSZ = (size_t)BSZ * NNODE * DK;  // 419.4 MB
  const size_t S = (size_t)BSZ * 512;
  float* K    = ws;
  float* Hbar = ws + KSZ;
  float* acc  = ws + KSZ + 1 * S;
  float* Q    = ws + KSZ + 2 * S;
  float* Hpi  = ws + KSZ + 3 * S;
  float* Hpi0 = ws + KSZ + 4 * S;

  // setup (all bit-faithful f32)
  k_hbar  <<<2048, 256, 0, stream>>>(H, Hbar);
  k_K     <<<BSZ * 25, 256, 0, stream>>>(H, WK, K);
  k_acc512<<<BSZ, 256, 0, stream>>>(Hbar, WQ, acc);
  k_q0    <<<BSZ, 256, 0, stream>>>(acc, WQ, v1, vf, Q);

  // step 0
  k_step  <<<BSZ, 256, 0, stream>>>(K, Q, H, Hpi, out, 0);
  k_copy  <<<2048, 256, 0, stream>>>(Hpi, Hpi0);  // freeze H_pi_1 = pick0

  // steps 1..199
  for (int i = 1; i < NSTEP; i++) {
    k_q   <<<BSZ / 4, 256, 0, stream>>>(acc, WQ, Hpi, Hpi0, Q);
    k_step<<<BSZ, 256, 0, stream>>>(K, Q, H, Hpi, out, i);
  }
}